// Round 1
// baseline (501.914 us; speedup 1.0000x reference)
//
#include <hip/hip_runtime.h>

// DynamicUpsamplingFilter: out[n][c*16+u][h][w] =
//   sum_p x_pad[n][c][h+i-2][w+j-2] * filters[n][p][u][h][w],  p = i*5+j
//
// Shapes: x (4,3,180,320) f32; filters (4,25,16,180,320) f32; out (4,48,180,320) f32.
// Memory-bound: filters = 368.6 MB read-once dominates. One thread per (n,u,h,w):
// 25 coalesced filter reads (read-once), 75 cached x reads, 3 accumulators,
// 3 coalesced stores. Padding via clamp + select (loads always in-bounds).

#define HH 180
#define WW 320
#define CC 3
#define UU 16
#define NN 4

__global__ __launch_bounds__(256) void duf_kernel(
    const float* __restrict__ x,
    const float* __restrict__ filters,
    float* __restrict__ out)
{
    const int HW = HH * WW;
    int idx = blockIdx.x * 256 + threadIdx.x;
    const int total = NN * UU * HW;
    if (idx >= total) return;

    int w = idx % WW;
    int t = idx / WW;
    int h = t % HH;
    t /= HH;
    int u = t % UU;
    int n = t / UU;

    // filters[n][p][u][h][w]: base at p=0, stride per p = 16*HW
    const float* fptr = filters + ((size_t)((n * 25) * UU + u) * HH + h) * WW + w;
    const float* xbase = x + (size_t)(n * CC) * HW;

    float acc0 = 0.f, acc1 = 0.f, acc2 = 0.f;

    #pragma unroll
    for (int i = 0; i < 5; ++i) {
        int hi = h + i - 2;
        bool rowv = (hi >= 0) & (hi < HH);
        int hic = min(max(hi, 0), HH - 1);
        #pragma unroll
        for (int j = 0; j < 5; ++j) {
            int wj = w + j - 2;
            bool v = rowv & (wj >= 0) & (wj < WW);
            int wjc = min(max(wj, 0), WW - 1);
            int p = i * 5 + j;

            float f = fptr[(size_t)p * UU * HW];
            int xo = hic * WW + wjc;
            float v0 = xbase[xo];
            float v1 = xbase[HW + xo];
            float v2 = xbase[2 * HW + xo];
            if (!v) { v0 = 0.f; v1 = 0.f; v2 = 0.f; }
            acc0 += v0 * f;
            acc1 += v1 * f;
            acc2 += v2 * f;
        }
    }

    // out[n][c*16+u][h][w]; base at c=0
    float* optr = out + ((size_t)(n * CC * UU + u) * HH + h) * WW + w;
    optr[0]                  = acc0;
    optr[(size_t)UU * HW]     = acc1;
    optr[(size_t)2 * UU * HW] = acc2;
}

extern "C" void kernel_launch(void* const* d_in, const int* in_sizes, int n_in,
                              void* d_out, int out_size, void* d_ws, size_t ws_size,
                              hipStream_t stream) {
    const float* x       = (const float*)d_in[0];
    const float* filters = (const float*)d_in[1];
    float* out           = (float*)d_out;

    const int total = NN * UU * HH * WW;        // 3,686,400 threads
    const int block = 256;
    const int grid = (total + block - 1) / block; // 14,400 blocks
    duf_kernel<<<grid, block, 0, stream>>>(x, filters, out);
}

// Round 2
// 496.568 us; speedup vs baseline: 1.0108x; 1.0108x over previous
//
#include <hip/hip_runtime.h>

// DynamicUpsamplingFilter, float32.
//   out[n][c*16+u][h][w] = sum_{i,j} xpad[n][c][h+i][w+j] * filters[n][i*5+j][u][h][w]
// x (4,3,180,320), filters (4,25,16,180,320)=368.6MB read-once, out (4,48,180,320)=44.2MB.
// Memory-bound (AI ~1.3 FLOP/B). Strategy: all VMEM as 16B/lane dwordx4.
//  K1: zero-pad x into d_ws as (4,3,184,328); WP=328 keeps rows 16B-aligned.
//  K2: thread = (n,u,h,w4) with w4 = 4 consecutive w. 25 filter float4 loads,
//      30 x float4 loads (8-float window/channel/row reused across 5 j-taps),
//      3 float4 stores. No edge branches.

#define HH 180
#define WW 320
#define CC 3
#define UU 16
#define NN 4
#define HP (HH + 4)      // 184
#define WP 328           // 320 + 4 pad + 4 align slack; 328*4B = 82*16B
#define HW (HH * WW)     // 57600
#define PHW (HP * WP)    // 60352

__global__ __launch_bounds__(256) void pad_x_kernel(
    const float* __restrict__ x, float* __restrict__ xpad)
{
    int idx = blockIdx.x * 256 + threadIdx.x;   // grid sized exactly
    int wp = idx % WP;
    int t  = idx / WP;
    int hp = t % HP;
    int nc = t / HP;                            // n*3 + c
    int h = hp - 2, w = wp - 2;
    float v = 0.f;
    if (h >= 0 && h < HH && w >= 0 && w < WW)
        v = x[(size_t)nc * HW + h * WW + w];
    xpad[idx] = v;
}

__global__ __launch_bounds__(256) void duf_kernel(
    const float* __restrict__ xpad,
    const float* __restrict__ filters,
    float* __restrict__ out)
{
    int idx = blockIdx.x * 256 + threadIdx.x;   // total 921600 = 3600*256 exact
    int w4 = idx % (WW / 4);
    int t  = idx / (WW / 4);
    int h  = t % HH;
    t /= HH;
    int u = t % UU;
    int n = t / UU;

    const int wbase = w4 * 4;
    const float* fptr = filters + (((size_t)n * 25 * UU + u) * HW + (size_t)h * WW + wbase);

    float acc[CC][4];
    #pragma unroll
    for (int c = 0; c < CC; ++c)
        #pragma unroll
        for (int q = 0; q < 4; ++q) acc[c][q] = 0.f;

    #pragma unroll
    for (int i = 0; i < 5; ++i) {
        // 8-float x window per channel for row h+i (padded coords)
        float xv[CC][8];
        #pragma unroll
        for (int c = 0; c < CC; ++c) {
            const float* xr = xpad + ((size_t)(n * CC + c) * HP + (h + i)) * WP + wbase;
            float4 a = *(const float4*)xr;
            float4 b = *(const float4*)(xr + 4);
            xv[c][0] = a.x; xv[c][1] = a.y; xv[c][2] = a.z; xv[c][3] = a.w;
            xv[c][4] = b.x; xv[c][5] = b.y; xv[c][6] = b.z; xv[c][7] = b.w;
        }
        #pragma unroll
        for (int j = 0; j < 5; ++j) {
            float4 f = *(const float4*)(fptr + (size_t)(i * 5 + j) * UU * HW);
            #pragma unroll
            for (int c = 0; c < CC; ++c) {
                acc[c][0] += xv[c][j + 0] * f.x;
                acc[c][1] += xv[c][j + 1] * f.y;
                acc[c][2] += xv[c][j + 2] * f.z;
                acc[c][3] += xv[c][j + 3] * f.w;
            }
        }
    }

    #pragma unroll
    for (int c = 0; c < CC; ++c) {
        float* op = out + (((size_t)n * CC * UU + c * UU + u) * HW + (size_t)h * WW + wbase);
        *(float4*)op = make_float4(acc[c][0], acc[c][1], acc[c][2], acc[c][3]);
    }
}

extern "C" void kernel_launch(void* const* d_in, const int* in_sizes, int n_in,
                              void* d_out, int out_size, void* d_ws, size_t ws_size,
                              hipStream_t stream) {
    const float* x       = (const float*)d_in[0];
    const float* filters = (const float*)d_in[1];
    float* out           = (float*)d_out;
    float* xpad          = (float*)d_ws;        // needs 4*3*184*328*4 = 2.9 MB

    const int pad_total = NN * CC * PHW;        // 724224 = 2829*256 exact
    pad_x_kernel<<<pad_total / 256, 256, 0, stream>>>(x, xpad);

    const int total = NN * UU * HH * (WW / 4);  // 921600 = 3600*256 exact
    duf_kernel<<<total / 256, 256, 0, stream>>>(xpad, filters, out);
}